// Round 2
// baseline (447.628 us; speedup 1.0000x reference)
//
#include <hip/hip_runtime.h>
#include <hip/hip_bf16.h>
#include <stdint.h>

// Q_Mlp: HAWQ-style quantized MLP on MI355X.
// B=256, S=196 -> M=50176 rows. D=384, H=1536.
// Exact-integer int8 GEMMs via v_mfma_i32_16x16x64_i8.
// Pipeline: quant W1/W2/x -> GEMM1 pass A (global max only) ->
//           GEMM1 pass B (emit int8 hq) -> GEMM2 (+|max|) into d_out ->
//           final per-tensor quantization in place, plus asf2 scalar.
// Workspace ~98 MB (no f32 h buffer -> avoids round-1's d_ws overflow fault).

#define M_TOT 50176
#define D_IN  384
#define H_MID 1536

typedef int v4i __attribute__((ext_vector_type(4)));

__device__ __forceinline__ float clamp_q(float q) {
  return fminf(fmaxf(q, -128.0f), 127.0f);
}

__device__ __forceinline__ void gld_lds16(const int8_t* g, int8_t* s) {
  __builtin_amdgcn_global_load_lds((const __attribute__((address_space(1))) void*)g,
                                   (__attribute__((address_space(3))) void*)s,
                                   16, 0, 0);
}

// One wave per weight row: row-max -> w_sf, int8 quantize, optional b_int.
__global__ void quant_w_kernel(const float* __restrict__ W, const float* __restrict__ b,
                               int8_t* __restrict__ Wq, float* __restrict__ wsf,
                               int* __restrict__ bint, const float* __restrict__ asf_p,
                               int cols) {
  const int lane = threadIdx.x & 63;
  const int row  = blockIdx.x * 4 + (threadIdx.x >> 6);
  const float* wr = W + (size_t)row * cols;
  float m = 0.f;
  for (int c = lane; c < cols; c += 64) m = fmaxf(m, fabsf(wr[c]));
#pragma unroll
  for (int off = 32; off; off >>= 1) m = fmaxf(m, __shfl_xor(m, off));
  const float sf = m / 127.0f;              // matches jnp: max/QMAX (f32 division)
  int8_t* qr = Wq + (size_t)row * cols;
  for (int c = lane; c < cols; c += 64)
    qr[c] = (int8_t)clamp_q(rintf(wr[c] / sf));   // round-half-even, f32 division
  if (lane == 0) {
    wsf[row] = sf;
    if (bint) bint[row] = (int)rintf(b[row] / (sf * asf_p[0]));
  }
}

__global__ void quant_x_kernel(const float4* __restrict__ x, char4* __restrict__ xq,
                               const float* __restrict__ asf_p, int n4) {
  const float asf = asf_p[0];
  const int stride = gridDim.x * blockDim.x;
  for (int i = blockIdx.x * blockDim.x + threadIdx.x; i < n4; i += stride) {
    float4 v = x[i];
    char4 q;
    q.x = (signed char)clamp_q(rintf(v.x / asf));
    q.y = (signed char)clamp_q(rintf(v.y / asf));
    q.z = (signed char)clamp_q(rintf(v.z / asf));
    q.w = (signed char)clamp_q(rintf(v.w / asf));
    xq[i] = q;
  }
}

// C[m,n] = sum_k A[m,k]*B[n,k]  (both K-major int8), 128x128 tile, BK=64,
// 4 waves each computing a 64x64 sub-tile via 4x4 grid of 16x16x64 i8 MFMAs.
// MODE 0: GEMM1 max pass  — no store; atomicMax( max(relu(h)) ).
// MODE 1: GEMM1 quant pass — store hq = clip(rint(relu(h)/sf1)) as int8.
// MODE 2: GEMM2           — store y_pre f32; atomicMax( max|y_pre| ).
template <int MODE>
__global__ __launch_bounds__(256) void gemm_i8_kernel(
    const int8_t* __restrict__ A, const int8_t* __restrict__ Bm,
    int M, int N, int K, int ntiles_n,
    const float* __restrict__ sfv, const int* __restrict__ bintv,
    const float* __restrict__ bias, const float* __restrict__ asf_p,
    const unsigned* __restrict__ gmax_in,
    float* __restrict__ Cout, int8_t* __restrict__ Cq,
    unsigned* __restrict__ gmax_out) {
  __shared__ __align__(16) int8_t sA[128 * 64];
  __shared__ __align__(16) int8_t sB[128 * 64];
  const int tid  = threadIdx.x;
  const int lane = tid & 63;
  const int wid  = tid >> 6;
  const int bn = blockIdx.x % ntiles_n;
  const int bm = blockIdx.x / ntiles_n;
  const int wm = (wid >> 1) * 64;
  const int wn = (wid & 1) * 64;
  const int l16  = lane & 15;
  const int koff = (lane >> 4) * 16;

  // staging: flat byte f covers LDS linearly; 4 x 16B global_load_lds per thread
  const int f    = tid * 16;
  const int srow = f >> 6;
  const int scol = f & 63;
  const int8_t* gA0 = A  + ((size_t)(bm * 128 + srow)) * K + scol;
  const int8_t* gB0 = Bm + ((size_t)(bn * 128 + srow)) * K + scol;
  const size_t rstep = (size_t)64 * K;

  v4i acc[4][4] = {};

  for (int kt = 0; kt < K; kt += 64) {
    gld_lds16(gA0 + kt,         sA + f);
    gld_lds16(gA0 + rstep + kt, sA + 4096 + f);
    gld_lds16(gB0 + kt,         sB + f);
    gld_lds16(gB0 + rstep + kt, sB + 4096 + f);
    __syncthreads();   // compiler emits s_waitcnt vmcnt(0) before s_barrier
    v4i va[4], vb[4];
#pragma unroll
    for (int i = 0; i < 4; ++i)
      va[i] = *(const v4i*)(sA + (wm + i * 16 + l16) * 64 + koff);
#pragma unroll
    for (int j = 0; j < 4; ++j)
      vb[j] = *(const v4i*)(sB + (wn + j * 16 + l16) * 64 + koff);
#pragma unroll
    for (int i = 0; i < 4; ++i)
#pragma unroll
      for (int j = 0; j < 4; ++j)
        acc[i][j] = __builtin_amdgcn_mfma_i32_16x16x64_i8(va[i], vb[j], acc[i][j], 0, 0, 0);
    __syncthreads();
  }

  // epilogue: C/D layout col = lane&15, row = (lane>>4)*4 + reg
  float lmax = 0.f;
  const int r0 = (lane >> 4) * 4;
  float sf1 = 0.f, asf = 0.f;
  if (MODE == 2) sf1 = __uint_as_float(*gmax_in) / 127.0f;     // asf for stage 2
  else           asf = asf_p[0];
  if (MODE == 1) sf1 = __uint_as_float(*gmax_in) / 127.0f;     // requant grid

#pragma unroll
  for (int j = 0; j < 4; ++j) {
    const int col = bn * 128 + wn + j * 16 + l16;
    float scale;
    int bi;
    if (MODE == 2) { scale = sfv[col] * sf1; bi = (int)rintf(bias[col] / scale); }
    else           { scale = sfv[col] * asf; bi = bintv[col]; }
#pragma unroll
    for (int i = 0; i < 4; ++i) {
      const int row = bm * 128 + wm + i * 16 + r0;
#pragma unroll
      for (int r = 0; r < 4; ++r) {
        float v = (float)(acc[i][j][r] + bi) * scale;  // int add exact, single f32 mul
        if (MODE == 0) {
          lmax = fmaxf(lmax, v);                        // relu-max: lmax init 0 covers relu
        } else if (MODE == 1) {
          v = fmaxf(v, 0.f);                            // relu
          Cq[(size_t)(row + r) * N + col] = (int8_t)clamp_q(rintf(v / sf1));
        } else {
          lmax = fmaxf(lmax, fabsf(v));
          Cout[(size_t)(row + r) * N + col] = v;
        }
      }
    }
  }
  if (MODE != 1) {
#pragma unroll
    for (int off = 32; off; off >>= 1) lmax = fmaxf(lmax, __shfl_xor(lmax, off));
    if (lane == 0) atomicMax(gmax_out, __float_as_uint(lmax));  // nonneg floats: uint order ok
  }
}

__global__ void final_quant_kernel(float* __restrict__ y, const unsigned* __restrict__ gmax,
                                   int n4) {
  const float asf2 = __uint_as_float(*gmax) / 127.0f;
  float4* y4 = (float4*)y;
  const int stride = gridDim.x * blockDim.x;
  for (int i = blockIdx.x * blockDim.x + threadIdx.x; i < n4; i += stride) {
    float4 v = y4[i];
    v.x = clamp_q(rintf(v.x / asf2)) * asf2;
    v.y = clamp_q(rintf(v.y / asf2)) * asf2;
    v.z = clamp_q(rintf(v.z / asf2)) * asf2;
    v.w = clamp_q(rintf(v.w / asf2)) * asf2;
    y4[i] = v;
  }
  if (blockIdx.x == 0 && threadIdx.x == 0) y[(size_t)n4 * 4] = asf2;  // output 1: asf2
}

extern "C" void kernel_launch(void* const* d_in, const int* in_sizes, int n_in,
                              void* d_out, int out_size, void* d_ws, size_t ws_size,
                              hipStream_t stream) {
  const float* x   = (const float*)d_in[0];
  const float* W1  = (const float*)d_in[1];
  const float* b1  = (const float*)d_in[2];
  const float* W2  = (const float*)d_in[3];
  const float* b2  = (const float*)d_in[4];
  const float* asf = (const float*)d_in[5];

  char* ws = (char*)d_ws;
  unsigned* gmax1 = (unsigned*)ws;        // max(relu(h)) (nonneg)
  unsigned* gmax2 = (unsigned*)(ws + 8);  // max|y_pre|
  size_t off = 256;
  int8_t* xq   = (int8_t*)(ws + off); off += (size_t)M_TOT * D_IN;   // 19.3 MB
  int8_t* w1q  = (int8_t*)(ws + off); off += (size_t)H_MID * D_IN;   // 0.6 MB
  float*  w1sf = (float*)(ws + off);  off += (size_t)H_MID * 4;
  int*    b1i  = (int*)(ws + off);    off += (size_t)H_MID * 4;
  int8_t* w2q  = (int8_t*)(ws + off); off += (size_t)D_IN * H_MID;   // 0.6 MB
  float*  w2sf = (float*)(ws + off);  off += (size_t)D_IN * 4;
  off = (off + 255) & ~(size_t)255;
  int8_t* hq   = (int8_t*)(ws + off); off += (size_t)M_TOT * H_MID;  // 77.1 MB
  // total ~97.6 MB — no f32 h buffer (round-1 crash: d_ws overflow at ~406 MB)

  hipMemsetAsync(d_ws, 0, 256, stream);  // reset global maxes every call

  quant_w_kernel<<<H_MID / 4, 256, 0, stream>>>(W1, b1, w1q, w1sf, b1i, asf, D_IN);
  quant_w_kernel<<<D_IN / 4, 256, 0, stream>>>(W2, nullptr, w2q, w2sf, nullptr, nullptr, H_MID);
  quant_x_kernel<<<2048, 256, 0, stream>>>((const float4*)x, (char4*)xq, asf,
                                           M_TOT * D_IN / 4);
  // GEMM1 pass A: global max(relu(h)) only
  gemm_i8_kernel<0><<<(M_TOT / 128) * (H_MID / 128), 256, 0, stream>>>(
      xq, w1q, M_TOT, H_MID, D_IN, H_MID / 128, w1sf, b1i, nullptr, asf, nullptr,
      nullptr, nullptr, gmax1);
  // GEMM1 pass B: emit int8 hq on the sf1 grid
  gemm_i8_kernel<1><<<(M_TOT / 128) * (H_MID / 128), 256, 0, stream>>>(
      xq, w1q, M_TOT, H_MID, D_IN, H_MID / 128, w1sf, b1i, nullptr, asf, gmax1,
      nullptr, hq, nullptr);
  // GEMM2: y_pre into d_out + max|y_pre|
  gemm_i8_kernel<2><<<(M_TOT / 128) * (D_IN / 128), 256, 0, stream>>>(
      hq, w2q, M_TOT, D_IN, H_MID, D_IN / 128, w2sf, nullptr, b2, nullptr, gmax1,
      (float*)d_out, nullptr, gmax2);
  final_quant_kernel<<<2048, 256, 0, stream>>>((float*)d_out, gmax2, M_TOT * D_IN / 4);
}

// Round 3
// 247.366 us; speedup vs baseline: 1.8096x; 1.8096x over previous
//
#include <hip/hip_runtime.h>
#include <hip/hip_bf16.h>
#include <stdint.h>

// Q_Mlp: HAWQ-style quantized MLP on MI355X (gfx950).
// B=256, S=196 -> M=50176 rows. D=384, H=1536.
// Exact-integer int8 GEMMs via v_mfma_i32_16x16x64_i8.
// Round 3: 2-phase prefetch double-buffer (T3-min), spread-slot atomics,
//          bijective XCD blockIdx swizzle (grids all divisible by 8).

#define M_TOT 50176
#define D_IN  384
#define H_MID 1536
#define NSLOT 256

typedef int v4i __attribute__((ext_vector_type(4)));

__device__ __forceinline__ float clamp_q(float q) {
  return fminf(fmaxf(q, -128.0f), 127.0f);
}

__device__ __forceinline__ void gld_lds16(const int8_t* g, int8_t* s) {
  __builtin_amdgcn_global_load_lds((const __attribute__((address_space(1))) void*)g,
                                   (__attribute__((address_space(3))) void*)s,
                                   16, 0, 0);
}

// One wave per weight row: row-max -> w_sf, int8 quantize, optional b_int.
__global__ void quant_w_kernel(const float* __restrict__ W, const float* __restrict__ b,
                               int8_t* __restrict__ Wq, float* __restrict__ wsf,
                               int* __restrict__ bint, const float* __restrict__ asf_p,
                               int cols) {
  const int lane = threadIdx.x & 63;
  const int row  = blockIdx.x * 4 + (threadIdx.x >> 6);
  const float* wr = W + (size_t)row * cols;
  float m = 0.f;
  for (int c = lane; c < cols; c += 64) m = fmaxf(m, fabsf(wr[c]));
#pragma unroll
  for (int off = 32; off; off >>= 1) m = fmaxf(m, __shfl_xor(m, off));
  const float sf = m / 127.0f;              // matches jnp: max/QMAX (f32 division)
  int8_t* qr = Wq + (size_t)row * cols;
  for (int c = lane; c < cols; c += 64)
    qr[c] = (int8_t)clamp_q(rintf(wr[c] / sf));   // round-half-even, f32 division
  if (lane == 0) {
    wsf[row] = sf;
    if (bint) bint[row] = (int)rintf(b[row] / (sf * asf_p[0]));
  }
}

__global__ void quant_x_kernel(const float4* __restrict__ x, char4* __restrict__ xq,
                               const float* __restrict__ asf_p, int n4) {
  const float asf = asf_p[0];
  const int stride = gridDim.x * blockDim.x;
  for (int i = blockIdx.x * blockDim.x + threadIdx.x; i < n4; i += stride) {
    float4 v = x[i];
    char4 q;
    q.x = (signed char)clamp_q(rintf(v.x / asf));
    q.y = (signed char)clamp_q(rintf(v.y / asf));
    q.z = (signed char)clamp_q(rintf(v.z / asf));
    q.w = (signed char)clamp_q(rintf(v.w / asf));
    xq[i] = q;
  }
}

// C[m,n] = sum_k A[m,k]*B[n,k]  (both K-major int8), 128x128 tile, BK=64,
// 2-phase prefetch: stage tile kt+1 into buf^1 while computing buf, one
// barrier per K-step (syncthreads drains vmcnt+lgkmcnt).
// MODE 0: GEMM1 max pass  — no store; per-wave atomicMax into slot array.
// MODE 1: GEMM1 quant pass — store hq int8 on sf1 grid (sf1 from slot reduce).
// MODE 2: GEMM2           — store y_pre f32; per-wave atomicMax |y_pre| slots.
template <int MODE>
__global__ __launch_bounds__(256) void gemm_i8_kernel(
    const int8_t* __restrict__ A, const int8_t* __restrict__ Bm,
    int N, int K, int ntiles_n,
    const float* __restrict__ sfv, const int* __restrict__ bintv,
    const float* __restrict__ bias, const float* __restrict__ asf_p,
    const unsigned* __restrict__ gmax_in,   // NSLOT slots
    float* __restrict__ Cout, int8_t* __restrict__ Cq,
    unsigned* __restrict__ gmax_out) {      // NSLOT slots
  __shared__ __align__(16) int8_t sA[2][8192];
  __shared__ __align__(16) int8_t sB[2][8192];
  const int tid  = threadIdx.x;
  const int lane = tid & 63;
  const int wid  = tid >> 6;
  // bijective XCD swizzle: HW block b runs on XCD b%8; give each XCD a
  // contiguous work-id range (grids here are all divisible by 8).
  const int cpx = gridDim.x >> 3;
  const int wg  = (blockIdx.x & 7) * cpx + (blockIdx.x >> 3);
  const int bn = wg % ntiles_n;
  const int bm = wg / ntiles_n;
  const int wm = (wid >> 1) * 64;
  const int wn = (wid & 1) * 64;
  const int l16  = lane & 15;
  const int koff = (lane >> 4) * 16;

  // staging: flat byte f = tid*16 covers each half-tile linearly
  const int f    = tid * 16;
  const int srow = tid >> 2;        // f >> 6
  const int scol = (tid & 3) * 16;  // f & 63
  const int8_t* gA0 = A  + ((size_t)(bm * 128 + srow)) * K + scol;
  const int8_t* gB0 = Bm + ((size_t)(bn * 128 + srow)) * K + scol;
  const size_t rstep = (size_t)64 * K;

  v4i acc[4][4] = {};
  const int kmax = K >> 6;

  // prologue: stage tile 0 into buf 0
  gld_lds16(gA0,         &sA[0][f]);
  gld_lds16(gA0 + rstep, &sA[0][4096 + f]);
  gld_lds16(gB0,         &sB[0][f]);
  gld_lds16(gB0 + rstep, &sB[0][4096 + f]);
  __syncthreads();

  for (int kt = 0; kt < kmax; ++kt) {
    const int cur = kt & 1;
    if (kt + 1 < kmax) {               // uniform branch
      const int kb = (kt + 1) << 6;
      gld_lds16(gA0 + kb,         &sA[cur ^ 1][f]);
      gld_lds16(gA0 + rstep + kb, &sA[cur ^ 1][4096 + f]);
      gld_lds16(gB0 + kb,         &sB[cur ^ 1][f]);
      gld_lds16(gB0 + rstep + kb, &sB[cur ^ 1][4096 + f]);
    }
    v4i va[4], vb[4];
#pragma unroll
    for (int i = 0; i < 4; ++i)
      va[i] = *(const v4i*)&sA[cur][(wm + i * 16 + l16) * 64 + koff];
#pragma unroll
    for (int j = 0; j < 4; ++j)
      vb[j] = *(const v4i*)&sB[cur][(wn + j * 16 + l16) * 64 + koff];
#pragma unroll
    for (int i = 0; i < 4; ++i)
#pragma unroll
      for (int j = 0; j < 4; ++j)
        acc[i][j] = __builtin_amdgcn_mfma_i32_16x16x64_i8(va[i], vb[j], acc[i][j], 0, 0, 0);
    __syncthreads();   // drains vmcnt (prefetch landed) + lgkmcnt; guards buf reuse
  }

  // sf1 for MODE 1/2: reduce the NSLOT slot array once per block (LDS free now)
  float sf1 = 0.f, asf = 0.f;
  if (MODE == 0) {
    asf = asf_p[0];
  } else {
    float* bcast = (float*)&sA[0][0];
    if (wid == 0) {
      float m = fmaxf(fmaxf(__uint_as_float(gmax_in[lane]),
                            __uint_as_float(gmax_in[lane + 64])),
                      fmaxf(__uint_as_float(gmax_in[lane + 128]),
                            __uint_as_float(gmax_in[lane + 192])));
#pragma unroll
      for (int off = 32; off; off >>= 1) m = fmaxf(m, __shfl_xor(m, off));
      if (lane == 0) *bcast = m / 127.0f;
    }
    __syncthreads();
    sf1 = *bcast;
    if (MODE == 1) asf = asf_p[0];
  }

  // epilogue: C/D layout col = lane&15, row = (lane>>4)*4 + reg
  float lmax = 0.f;
  const int r0 = (lane >> 4) * 4;
#pragma unroll
  for (int j = 0; j < 4; ++j) {
    const int col = bn * 128 + wn + j * 16 + l16;
    float scale;
    int bi;
    if (MODE == 2) { scale = sfv[col] * sf1; bi = (int)rintf(bias[col] / scale); }
    else           { scale = sfv[col] * asf; bi = bintv[col]; }
#pragma unroll
    for (int i = 0; i < 4; ++i) {
      const int row = bm * 128 + wm + i * 16 + r0;
#pragma unroll
      for (int r = 0; r < 4; ++r) {
        float v = (float)(acc[i][j][r] + bi) * scale;  // int add exact, single f32 mul
        if (MODE == 0) {
          lmax = fmaxf(lmax, v);                        // relu-max (lmax>=0 covers relu)
        } else if (MODE == 1) {
          v = fmaxf(v, 0.f);                            // relu
          Cq[(size_t)(row + r) * N + col] = (int8_t)clamp_q(rintf(v / sf1));
        } else {
          lmax = fmaxf(lmax, fabsf(v));
          Cout[(size_t)(row + r) * N + col] = v;
        }
      }
    }
  }
  if (MODE != 1) {
#pragma unroll
    for (int off = 32; off; off >>= 1) lmax = fmaxf(lmax, __shfl_xor(lmax, off));
    // one atomic per wave, spread over NSLOT slots (nonneg: uint order == float order)
    if (lane == 0) atomicMax(&gmax_out[(wg * 4 + wid) & (NSLOT - 1)], __float_as_uint(lmax));
  }
}

__global__ void final_quant_kernel(float* __restrict__ y, const unsigned* __restrict__ slots,
                                   int n4) {
  __shared__ float s_sf;
  const int tid = threadIdx.x;
  if (tid < 64) {
    float m = fmaxf(fmaxf(__uint_as_float(slots[tid]),
                          __uint_as_float(slots[tid + 64])),
                    fmaxf(__uint_as_float(slots[tid + 128]),
                          __uint_as_float(slots[tid + 192])));
#pragma unroll
    for (int off = 32; off; off >>= 1) m = fmaxf(m, __shfl_xor(m, off));
    if (tid == 0) s_sf = m / 127.0f;
  }
  __syncthreads();
  const float asf2 = s_sf;
  float4* y4 = (float4*)y;
  const int stride = gridDim.x * blockDim.x;
  for (int i = blockIdx.x * blockDim.x + tid; i < n4; i += stride) {
    float4 v = y4[i];
    v.x = clamp_q(rintf(v.x / asf2)) * asf2;
    v.y = clamp_q(rintf(v.y / asf2)) * asf2;
    v.z = clamp_q(rintf(v.z / asf2)) * asf2;
    v.w = clamp_q(rintf(v.w / asf2)) * asf2;
    y4[i] = v;
  }
  if (blockIdx.x == 0 && tid == 0) y[(size_t)n4 * 4] = asf2;  // output 1: asf2
}

extern "C" void kernel_launch(void* const* d_in, const int* in_sizes, int n_in,
                              void* d_out, int out_size, void* d_ws, size_t ws_size,
                              hipStream_t stream) {
  const float* x   = (const float*)d_in[0];
  const float* W1  = (const float*)d_in[1];
  const float* b1  = (const float*)d_in[2];
  const float* W2  = (const float*)d_in[3];
  const float* b2  = (const float*)d_in[4];
  const float* asf = (const float*)d_in[5];

  char* ws = (char*)d_ws;
  unsigned* gmax1 = (unsigned*)ws;           // NSLOT slots: max(relu(h))
  unsigned* gmax2 = (unsigned*)(ws + 1024);  // NSLOT slots: max|y_pre|
  size_t off = 4096;
  int8_t* xq   = (int8_t*)(ws + off); off += (size_t)M_TOT * D_IN;   // 19.3 MB
  int8_t* w1q  = (int8_t*)(ws + off); off += (size_t)H_MID * D_IN;   // 0.6 MB
  float*  w1sf = (float*)(ws + off);  off += (size_t)H_MID * 4;
  int*    b1i  = (int*)(ws + off);    off += (size_t)H_MID * 4;
  int8_t* w2q  = (int8_t*)(ws + off); off += (size_t)D_IN * H_MID;   // 0.6 MB
  float*  w2sf = (float*)(ws + off);  off += (size_t)D_IN * 4;
  off = (off + 255) & ~(size_t)255;
  int8_t* hq   = (int8_t*)(ws + off); off += (size_t)M_TOT * H_MID;  // 77.1 MB

  hipMemsetAsync(d_ws, 0, 4096, stream);  // zero both slot arrays every call

  quant_w_kernel<<<H_MID / 4, 256, 0, stream>>>(W1, b1, w1q, w1sf, b1i, asf, D_IN);
  quant_w_kernel<<<D_IN / 4, 256, 0, stream>>>(W2, nullptr, w2q, w2sf, nullptr, nullptr, H_MID);
  quant_x_kernel<<<2048, 256, 0, stream>>>((const float4*)x, (char4*)xq, asf,
                                           M_TOT * D_IN / 4);
  // GEMM1 pass A: global max(relu(h)) only (grid 4704 = 8*588)
  gemm_i8_kernel<0><<<(M_TOT / 128) * (H_MID / 128), 256, 0, stream>>>(
      xq, w1q, H_MID, D_IN, H_MID / 128, w1sf, b1i, nullptr, asf, nullptr,
      nullptr, nullptr, gmax1);
  // GEMM1 pass B: emit int8 hq on the sf1 grid
  gemm_i8_kernel<1><<<(M_TOT / 128) * (H_MID / 128), 256, 0, stream>>>(
      xq, w1q, H_MID, D_IN, H_MID / 128, w1sf, b1i, nullptr, asf, gmax1,
      nullptr, hq, nullptr);
  // GEMM2: y_pre into d_out + max|y_pre| (grid 1176 = 8*147)
  gemm_i8_kernel<2><<<(M_TOT / 128) * (D_IN / 128), 256, 0, stream>>>(
      hq, w2q, D_IN, H_MID, D_IN / 128, w2sf, nullptr, b2, nullptr, gmax1,
      (float*)d_out, nullptr, gmax2);
  final_quant_kernel<<<2048, 256, 0, stream>>>((float*)d_out, gmax2, M_TOT * D_IN / 4);
}